// Round 1
// baseline (424.036 us; speedup 1.0000x reference)
//
#include <hip/hip_runtime.h>
#include <cstdint>
#include <cstddef>

typedef int v4i __attribute__((ext_vector_type(4)));

#define DI static __device__ __forceinline__

DI unsigned fmap(float f){ unsigned b=__float_as_uint(f); return (b&0x80000000u)? ~b : (b|0x80000000u); }
DI float funmap(unsigned u){ return (u&0x80000000u)? __uint_as_float(u&0x7fffffffu) : __uint_as_float(~u); }
DI float gelu_f(float x){ return 0.5f*x*(1.0f+erff(x*0.70710678118654752440f)); }

constexpr int Mtok = 12608;   // 64*197 tokens
constexpr int Cdim = 768;
constexpr int Hdim = 3072;
constexpr int MP   = 12672;   // 99*128 padded rows

// ---------------- init reduction slots ----------------
__global__ void k_init(unsigned* scal, unsigned* xminU, unsigned* xmaxU, unsigned* wmaxU){
    int t = blockIdx.x*256 + threadIdx.x;
    if (t < Cdim){
        xminU[t] = fmap(__builtin_inff());
        xmaxU[t] = fmap(-__builtin_inff());
        wmaxU[t] = fmap(0.0f);
    }
    if (t == 0){
        scal[0] = fmap(0.0f);               // habs (absmax of gelu(h))
        scal[1] = fmap(__builtin_inff());   // out min
        scal[2] = fmap(-__builtin_inff());  // out max
    }
}

// ---------------- per-channel min/max of x ----------------
__global__ void k_colstats_x(const float* __restrict__ x, unsigned* xminU, unsigned* xmaxU){
    int t = threadIdx.x;
    float mn0= __builtin_inff(), mn1= __builtin_inff(), mn2= __builtin_inff();
    float mx0=-__builtin_inff(), mx1=-__builtin_inff(), mx2=-__builtin_inff();
    for (int r = blockIdx.x; r < Mtok; r += gridDim.x){
        const float* row = x + (size_t)r*Cdim;
        float v0=row[t], v1=row[t+256], v2=row[t+512];
        mn0=fminf(mn0,v0); mx0=fmaxf(mx0,v0);
        mn1=fminf(mn1,v1); mx1=fmaxf(mx1,v1);
        mn2=fminf(mn2,v2); mx2=fmaxf(mx2,v2);
    }
    atomicMin(&xminU[t      ], fmap(mn0)); atomicMax(&xmaxU[t      ], fmap(mx0));
    atomicMin(&xminU[t+256  ], fmap(mn1)); atomicMax(&xmaxU[t+256  ], fmap(mx1));
    atomicMin(&xminU[t+512  ], fmap(mn2)); atomicMax(&xmaxU[t+512  ], fmap(mx2));
}

// ---------------- per-channel absmax of w1 (over rows) ----------------
__global__ void k_colmax_w1(const float* __restrict__ w1, unsigned* wmaxU){
    int t = threadIdx.x;
    float m0=0.f, m1=0.f, m2=0.f;
    for (int r = blockIdx.x; r < Hdim; r += gridDim.x){
        const float* row = w1 + (size_t)r*Cdim;
        m0=fmaxf(m0,fabsf(row[t]));
        m1=fmaxf(m1,fabsf(row[t+256]));
        m2=fmaxf(m2,fabsf(row[t+512]));
    }
    atomicMax(&wmaxU[t      ], fmap(m0));
    atomicMax(&wmaxU[t+256  ], fmap(m1));
    atomicMax(&wmaxU[t+512  ], fmap(m2));
}

// ---------------- cs[c] pow2 snap + activation scale/zp ----------------
__global__ void k_scale0(const unsigned* xminU, const unsigned* xmaxU, const unsigned* wmaxU,
                         float* cs, unsigned* scal){
    __shared__ float smn[256], smx[256];
    int t = threadIdx.x;
    float lmn =  __builtin_inff(), lmx = -__builtin_inff();
    #pragma unroll
    for (int j = 0; j < 3; ++j){
        int c = t + j*256;
        float xn = funmap(xminU[c]), xm = funmap(xmaxU[c]), wm = funmap(wmaxU[c]);
        float g  = fmaxf(fabsf(xn), fabsf(xm));
        float csr = powf(g, 0.5f) / powf(wm, 0.5f);
        float y = floorf(logf(csr) / 0.6931471805599453f);
        float p = exp2f(y);
        float c2 = exp2f(y + (((csr - p) > (2.0f*p - csr)) ? 1.0f : 0.0f));
        cs[c] = c2;
        lmn = fminf(lmn, xn / c2);
        lmx = fmaxf(lmx, xm / c2);
    }
    smn[t]=lmn; smx[t]=lmx; __syncthreads();
    for (int s=128; s; s>>=1){
        if (t < s){ smn[t]=fminf(smn[t],smn[t+s]); smx[t]=fmaxf(smx[t],smx[t+s]); }
        __syncthreads();
    }
    if (t == 0){
        float xmin_t = fminf(smn[0], 0.0f);
        float xmax_t = fmaxf(smx[0], 0.0f);
        float sc = fmaxf((xmax_t - xmin_t)/255.0f, 1e-8f);
        float zp = rintf(-xmin_t/sc);
        float* fs = (float*)scal;
        fs[8] = sc; fs[9] = zp;
    }
}

// ---------------- quantize w1 (smoothed, per-row symmetric) ----------------
__global__ void k_quant_w1(const float* __restrict__ w1, const float* __restrict__ cs,
                           const unsigned* scal, int8_t* __restrict__ qw1,
                           float* sa1, int* icorr1){
    __shared__ float sm[256];
    __shared__ int   si[256];
    int h = blockIdx.x, t = threadIdx.x;
    const float* wr = w1 + (size_t)h*Cdim;
    float v0 = wr[t]*cs[t], v1 = wr[t+256]*cs[t+256], v2 = wr[t+512]*cs[t+512];
    float am = fmaxf(fabsf(v0), fmaxf(fabsf(v1), fabsf(v2)));
    sm[t]=am; __syncthreads();
    for (int s=128; s; s>>=1){ if (t<s) sm[t]=fmaxf(sm[t],sm[t+s]); __syncthreads(); }
    float scale = fmaxf(sm[0]/127.0f, 1e-8f);
    float q0 = fminf(fmaxf(rintf(v0/scale), -128.0f), 127.0f);
    float q1 = fminf(fmaxf(rintf(v1/scale), -128.0f), 127.0f);
    float q2 = fminf(fmaxf(rintf(v2/scale), -128.0f), 127.0f);
    qw1[(size_t)h*Cdim + t      ] = (int8_t)q0;
    qw1[(size_t)h*Cdim + t + 256] = (int8_t)q1;
    qw1[(size_t)h*Cdim + t + 512] = (int8_t)q2;
    si[t] = (int)q0 + (int)q1 + (int)q2; __syncthreads();
    for (int s=128; s; s>>=1){ if (t<s) si[t]+=si[t+s]; __syncthreads(); }
    if (t == 0){
        const float* fs = (const float*)scal;
        sa1[h]    = fs[8]*scale;
        icorr1[h] = (128 - (int)fs[9]) * si[0];
    }
}

// ---------------- quantize w2 (per-row symmetric) ----------------
__global__ void k_quant_w2(const float* __restrict__ w2, int8_t* __restrict__ qw2, float* sa2){
    __shared__ float sm[256];
    int c = blockIdx.x, t = threadIdx.x;
    const float* wr = w2 + (size_t)c*Hdim;
    float v[12]; float am = 0.f;
    #pragma unroll
    for (int j=0;j<12;++j){ v[j]=wr[t + j*256]; am=fmaxf(am,fabsf(v[j])); }
    sm[t]=am; __syncthreads();
    for (int s=128; s; s>>=1){ if (t<s) sm[t]=fmaxf(sm[t],sm[t+s]); __syncthreads(); }
    float scale = fmaxf(sm[0]/127.0f, 1e-8f);
    #pragma unroll
    for (int j=0;j<12;++j){
        float q = fminf(fmaxf(rintf(v[j]/scale), -128.0f), 127.0f);
        qw2[(size_t)c*Hdim + t + j*256] = (int8_t)q;
    }
    if (t == 0) sa2[c] = scale;
}

// ---------------- quantize x (asym, recentered by -128) ----------------
__global__ void k_quant_x(const float* __restrict__ x, const float* __restrict__ cs,
                          const unsigned* scal, int8_t* __restrict__ qxs){
    int idx = blockIdx.x*256 + threadIdx.x;
    const int total = Mtok*(Cdim/4);
    if (idx >= total) return;
    const float* fs = (const float*)scal;
    float sc = fs[8], zp = fs[9];
    float4 v = ((const float4*)x)[idx];
    int cb = (idx % (Cdim/4))*4;
    float q0 = fminf(fmaxf(rintf((v.x/cs[cb+0])/sc)+zp, 0.f), 255.f);
    float q1 = fminf(fmaxf(rintf((v.y/cs[cb+1])/sc)+zp, 0.f), 255.f);
    float q2 = fminf(fmaxf(rintf((v.z/cs[cb+2])/sc)+zp, 0.f), 255.f);
    float q3 = fminf(fmaxf(rintf((v.w/cs[cb+3])/sc)+zp, 0.f), 255.f);
    uint32_t pack =  (uint32_t)(uint8_t)((int)q0-128)
                  | ((uint32_t)(uint8_t)((int)q1-128) << 8)
                  | ((uint32_t)(uint8_t)((int)q2-128) << 16)
                  | ((uint32_t)(uint8_t)((int)q3-128) << 24);
    ((uint32_t*)qxs)[idx] = pack;
}

// ---------------- int8 GEMM, 128x128 tile, mfma_i32_16x16x64_i8 ----------------
#define GLL(src,dst) __builtin_amdgcn_global_load_lds( \
    (const __attribute__((address_space(1))) unsigned*)(src), \
    (__attribute__((address_space(3))) unsigned*)(dst), 16, 0, 0)

// MODE 0: fc1 epilogue, absmax(gelu(h)) only
// MODE 1: fc1 epilogue, quantize gelu(h) -> int8 qout
// MODE 2: fc2 epilogue, out_pre fp32 + global min/max
template<int KSTEPS, int MODE>
__global__ __launch_bounds__(256)
void k_gemm(const int8_t* __restrict__ A, const int8_t* __restrict__ Bw, int N,
            const float* __restrict__ sa, const int* __restrict__ icorr,
            const float* __restrict__ bias, const unsigned* __restrict__ scal,
            int8_t* __restrict__ qout, float* __restrict__ fout,
            unsigned* __restrict__ r0, unsigned* __restrict__ r1)
{
    constexpr int K = KSTEPS*64;
    __shared__ __align__(16) int8_t As[8192];
    __shared__ __align__(16) int8_t Bs[8192];
    __shared__ float sred[8];
    int t = threadIdx.x, lane = t & 63, wid = t >> 6;
    int wr = wid >> 1, wc = wid & 1;
    size_t brow = (size_t)blockIdx.x * 128;
    int bcol = blockIdx.y * 128;

    int srow = t >> 2;
    int schunk = (t & 3) ^ ((srow >> 1) & 3);
    const int8_t* ga0 = A  + (brow + srow)*(size_t)K + schunk*16;
    const int8_t* gb0 = Bw + (size_t)(bcol + srow)*K + schunk*16;

    int rsw  = ((lane >> 4) ^ ((lane >> 1) & 3)) << 4;
    int aoff = ((wr*64 + (lane & 15)) << 6) + rsw;
    int boff = ((wc*64 + (lane & 15)) << 6) + rsw;

    v4i acc[4][4] = {};
    for (int ks = 0; ks < KSTEPS; ++ks){
        __syncthreads();
        const int8_t* pa = ga0 + ks*64;
        const int8_t* pb = gb0 + ks*64;
        GLL(pa,                   As + t*16);
        GLL(pa + (size_t)64*K,    As + 4096 + t*16);
        GLL(pb,                   Bs + t*16);
        GLL(pb + (size_t)64*K,    Bs + 4096 + t*16);
        __syncthreads();
        v4i a[4], b[4];
        #pragma unroll
        for (int m=0;m<4;++m) a[m] = *(const v4i*)(As + aoff + (m<<10));
        #pragma unroll
        for (int n=0;n<4;++n) b[n] = *(const v4i*)(Bs + boff + (n<<10));
        #pragma unroll
        for (int m=0;m<4;++m)
            #pragma unroll
            for (int n=0;n<4;++n)
                acc[m][n] = __builtin_amdgcn_mfma_i32_16x16x64_i8(a[m], b[n], acc[m][n], 0, 0, 0);
    }

    int rl = (lane >> 4) * 4;
    if (MODE == 0){
        float amax = 0.f;
        #pragma unroll
        for (int n=0;n<4;++n){
            int col = bcol + wc*64 + n*16 + (lane & 15);
            float s = sa[col]; int ic = icorr[col]; float bb = bias[col];
            #pragma unroll
            for (int m=0;m<4;++m){
                size_t row = brow + wr*64 + m*16 + rl;
                #pragma unroll
                for (int r=0;r<4;++r){
                    if (row + r < (size_t)Mtok){
                        float g = gelu_f(s*(float)(acc[m][n][r] + ic) + bb);
                        amax = fmaxf(amax, fabsf(g));
                    }
                }
            }
        }
        #pragma unroll
        for (int off=32; off; off>>=1) amax = fmaxf(amax, __shfl_down(amax, off));
        if (lane == 0) sred[wid] = amax;
        __syncthreads();
        if (t == 0) atomicMax(r0, fmap(fmaxf(fmaxf(sred[0],sred[1]), fmaxf(sred[2],sred[3]))));
    } else if (MODE == 1){
        float sh = fmaxf(funmap(*scal)/127.0f, 1e-8f);
        #pragma unroll
        for (int n=0;n<4;++n){
            int col = bcol + wc*64 + n*16 + (lane & 15);
            float s = sa[col]; int ic = icorr[col]; float bb = bias[col];
            #pragma unroll
            for (int m=0;m<4;++m){
                size_t row = brow + wr*64 + m*16 + rl;
                #pragma unroll
                for (int r=0;r<4;++r){
                    if (row + r < (size_t)Mtok){
                        float g = gelu_f(s*(float)(acc[m][n][r] + ic) + bb);
                        float q = fminf(fmaxf(rintf(g/sh), -128.0f), 127.0f);
                        qout[(row + r)*(size_t)N + col] = (int8_t)q;
                    }
                }
            }
        }
    } else {
        float sh = fmaxf(funmap(*scal)/127.0f, 1e-8f);
        float lmin =  __builtin_inff(), lmax = -__builtin_inff();
        #pragma unroll
        for (int n=0;n<4;++n){
            int col = bcol + wc*64 + n*16 + (lane & 15);
            float s = sh * sa[col]; float bb = bias[col];
            #pragma unroll
            for (int m=0;m<4;++m){
                size_t row = brow + wr*64 + m*16 + rl;
                #pragma unroll
                for (int r=0;r<4;++r){
                    if (row + r < (size_t)Mtok){
                        float o = s*(float)acc[m][n][r] + bb;
                        fout[(row + r)*(size_t)N + col] = o;
                        lmin = fminf(lmin, o); lmax = fmaxf(lmax, o);
                    }
                }
            }
        }
        #pragma unroll
        for (int off=32; off; off>>=1){
            lmin = fminf(lmin, __shfl_down(lmin, off));
            lmax = fmaxf(lmax, __shfl_down(lmax, off));
        }
        if (lane == 0){ sred[wid] = lmin; sred[4+wid] = lmax; }
        __syncthreads();
        if (t == 0){
            atomicMin(r0, fmap(fminf(fminf(sred[0],sred[1]), fminf(sred[2],sred[3]))));
            atomicMax(r1, fmap(fmaxf(fmaxf(sred[4],sred[5]), fmaxf(sred[6],sred[7]))));
        }
    }
}

// ---------------- final asym requant of out ----------------
__global__ void k_final(const float* __restrict__ outpre, const unsigned* __restrict__ scal,
                        float* __restrict__ out){
    int idx = blockIdx.x*256 + threadIdx.x;
    const int total = Mtok*(Cdim/4);
    if (idx >= total) return;
    float omin = fminf(funmap(scal[1]), 0.0f);
    float omax = fmaxf(funmap(scal[2]), 0.0f);
    float sc = fmaxf((omax - omin)/255.0f, 1e-8f);
    float zp = rintf(-omin/sc);
    float4 v = ((const float4*)outpre)[idx];
    v.x = (fminf(fmaxf(rintf(v.x/sc)+zp, 0.f), 255.f) - zp)*sc;
    v.y = (fminf(fmaxf(rintf(v.y/sc)+zp, 0.f), 255.f) - zp)*sc;
    v.z = (fminf(fmaxf(rintf(v.z/sc)+zp, 0.f), 255.f) - zp)*sc;
    v.w = (fminf(fmaxf(rintf(v.w/sc)+zp, 0.f), 255.f) - zp)*sc;
    ((float4*)out)[idx] = v;
}

extern "C" void kernel_launch(void* const* d_in, const int* in_sizes, int n_in,
                              void* d_out, int out_size, void* d_ws, size_t ws_size,
                              hipStream_t stream)
{
    if (n_in < 5) return;
    const float* x  = (const float*)d_in[0];
    const float* w1 = (const float*)d_in[1];
    const float* b1 = (const float*)d_in[2];
    const float* w2 = (const float*)d_in[3];
    const float* b2 = (const float*)d_in[4];
    float* out = (float*)d_out;

    uint8_t* w = (uint8_t*)d_ws;
    size_t off = 0;
    unsigned* scal  = (unsigned*)(w + off); off += 256;
    unsigned* xminU = (unsigned*)(w + off); off += 3072;
    unsigned* xmaxU = (unsigned*)(w + off); off += 3072;
    unsigned* wmaxU = (unsigned*)(w + off); off += 3072;
    float*    cs    = (float*)   (w + off); off += 3072;
    float*    sa1   = (float*)   (w + off); off += 12288;
    int*      icorr1= (int*)     (w + off); off += 12288;
    float*    sa2   = (float*)   (w + off); off += 3072;
    off = (off + 255) & ~(size_t)255;
    int8_t*   qw1   = (int8_t*)  (w + off); off += (size_t)Hdim*Cdim;
    int8_t*   qw2   = (int8_t*)  (w + off); off += (size_t)Cdim*Hdim;
    int8_t*   qxs   = (int8_t*)  (w + off); off += (size_t)MP*Cdim;
    int8_t*   qh    = (int8_t*)  (w + off); off += (size_t)MP*Hdim;
    float*    outpre= (float*)   (w + off); off += (size_t)Mtok*Cdim*4;
    if (ws_size < off) return;

    k_init<<<3, 256, 0, stream>>>(scal, xminU, xmaxU, wmaxU);
    k_colstats_x<<<512, 256, 0, stream>>>(x, xminU, xmaxU);
    k_colmax_w1<<<512, 256, 0, stream>>>(w1, wmaxU);
    k_scale0<<<1, 256, 0, stream>>>(xminU, xmaxU, wmaxU, cs, scal);
    k_quant_w1<<<Hdim, 256, 0, stream>>>(w1, cs, scal, qw1, sa1, icorr1);
    k_quant_w2<<<Cdim, 256, 0, stream>>>(w2, qw2, sa2);
    k_quant_x<<<(Mtok*(Cdim/4) + 255)/256, 256, 0, stream>>>(x, cs, scal, qxs);

    k_gemm<12,0><<<dim3(99,24), 256, 0, stream>>>(qxs, qw1, Hdim, sa1, icorr1, b1, scal,
                                                  nullptr, nullptr, &scal[0], nullptr);
    k_gemm<12,1><<<dim3(99,24), 256, 0, stream>>>(qxs, qw1, Hdim, sa1, icorr1, b1, scal,
                                                  qh, nullptr, nullptr, nullptr);
    k_gemm<48,2><<<dim3(99,6), 256, 0, stream>>>(qh, qw2, Cdim, sa2, nullptr, b2, scal,
                                                 nullptr, outpre, &scal[1], &scal[2]);

    k_final<<<(Mtok*(Cdim/4) + 255)/256, 256, 0, stream>>>(outpre, scal, out);
}

// Round 2
// 381.972 us; speedup vs baseline: 1.1101x; 1.1101x over previous
//
#include <hip/hip_runtime.h>
#include <cstdint>
#include <cstddef>

typedef int v4i __attribute__((ext_vector_type(4)));

#define DI static __device__ __forceinline__

DI unsigned fmap(float f){ unsigned b=__float_as_uint(f); return (b&0x80000000u)? ~b : (b|0x80000000u); }
DI float funmap(unsigned u){ return (u&0x80000000u)? __uint_as_float(u&0x7fffffffu) : __uint_as_float(~u); }
DI float gelu_f(float x){ return 0.5f*x*(1.0f+erff(x*0.70710678118654752440f)); }

constexpr int Mtok = 12608;   // 64*197 tokens
constexpr int Cdim = 768;
constexpr int Hdim = 3072;
constexpr int MP   = 12672;   // 99*128 padded rows

// ---------------- init reduction slots ----------------
__global__ void k_init(unsigned* scal, unsigned* xminU, unsigned* xmaxU, unsigned* wmaxU){
    int t = blockIdx.x*256 + threadIdx.x;
    if (t < Cdim){
        xminU[t] = fmap(__builtin_inff());
        xmaxU[t] = fmap(-__builtin_inff());
        wmaxU[t] = fmap(0.0f);
    }
    if (t == 0){
        scal[0] = fmap(0.0f);               // habs (absmax of gelu(h))
        scal[1] = fmap(__builtin_inff());   // out min
        scal[2] = fmap(-__builtin_inff());  // out max
    }
}

// ---------------- per-channel min/max of x ----------------
__global__ void k_colstats_x(const float* __restrict__ x, unsigned* xminU, unsigned* xmaxU){
    int t = threadIdx.x;
    float mn0= __builtin_inff(), mn1= __builtin_inff(), mn2= __builtin_inff();
    float mx0=-__builtin_inff(), mx1=-__builtin_inff(), mx2=-__builtin_inff();
    for (int r = blockIdx.x; r < Mtok; r += gridDim.x){
        const float* row = x + (size_t)r*Cdim;
        float v0=row[t], v1=row[t+256], v2=row[t+512];
        mn0=fminf(mn0,v0); mx0=fmaxf(mx0,v0);
        mn1=fminf(mn1,v1); mx1=fmaxf(mx1,v1);
        mn2=fminf(mn2,v2); mx2=fmaxf(mx2,v2);
    }
    atomicMin(&xminU[t      ], fmap(mn0)); atomicMax(&xmaxU[t      ], fmap(mx0));
    atomicMin(&xminU[t+256  ], fmap(mn1)); atomicMax(&xmaxU[t+256  ], fmap(mx1));
    atomicMin(&xminU[t+512  ], fmap(mn2)); atomicMax(&xmaxU[t+512  ], fmap(mx2));
}

// ---------------- per-channel absmax of w1 (over rows) ----------------
__global__ void k_colmax_w1(const float* __restrict__ w1, unsigned* wmaxU){
    int t = threadIdx.x;
    float m0=0.f, m1=0.f, m2=0.f;
    for (int r = blockIdx.x; r < Hdim; r += gridDim.x){
        const float* row = w1 + (size_t)r*Cdim;
        m0=fmaxf(m0,fabsf(row[t]));
        m1=fmaxf(m1,fabsf(row[t+256]));
        m2=fmaxf(m2,fabsf(row[t+512]));
    }
    atomicMax(&wmaxU[t      ], fmap(m0));
    atomicMax(&wmaxU[t+256  ], fmap(m1));
    atomicMax(&wmaxU[t+512  ], fmap(m2));
}

// ---------------- cs[c] pow2 snap + activation scale/zp ----------------
__global__ void k_scale0(const unsigned* xminU, const unsigned* xmaxU, const unsigned* wmaxU,
                         float* cs, unsigned* scal){
    __shared__ float smn[256], smx[256];
    int t = threadIdx.x;
    float lmn =  __builtin_inff(), lmx = -__builtin_inff();
    #pragma unroll
    for (int j = 0; j < 3; ++j){
        int c = t + j*256;
        float xn = funmap(xminU[c]), xm = funmap(xmaxU[c]), wm = funmap(wmaxU[c]);
        float g  = fmaxf(fabsf(xn), fabsf(xm));
        float csr = powf(g, 0.5f) / powf(wm, 0.5f);
        float y = floorf(logf(csr) / 0.6931471805599453f);
        float p = exp2f(y);
        float c2 = exp2f(y + (((csr - p) > (2.0f*p - csr)) ? 1.0f : 0.0f));
        cs[c] = c2;
        lmn = fminf(lmn, xn / c2);
        lmx = fmaxf(lmx, xm / c2);
    }
    smn[t]=lmn; smx[t]=lmx; __syncthreads();
    for (int s=128; s; s>>=1){
        if (t < s){ smn[t]=fminf(smn[t],smn[t+s]); smx[t]=fmaxf(smx[t],smx[t+s]); }
        __syncthreads();
    }
    if (t == 0){
        float xmin_t = fminf(smn[0], 0.0f);
        float xmax_t = fmaxf(smx[0], 0.0f);
        float sc = fmaxf((xmax_t - xmin_t)/255.0f, 1e-8f);
        float zp = rintf(-xmin_t/sc);
        float* fs = (float*)scal;
        fs[8] = sc; fs[9] = zp;
    }
}

// ---------------- quantize w1 (smoothed, per-row symmetric) ----------------
__global__ void k_quant_w1(const float* __restrict__ w1, const float* __restrict__ cs,
                           const unsigned* scal, int8_t* __restrict__ qw1,
                           float* sa1, int* icorr1){
    __shared__ float sm[256];
    __shared__ int   si[256];
    int h = blockIdx.x, t = threadIdx.x;
    const float* wr = w1 + (size_t)h*Cdim;
    float v0 = wr[t]*cs[t], v1 = wr[t+256]*cs[t+256], v2 = wr[t+512]*cs[t+512];
    float am = fmaxf(fabsf(v0), fmaxf(fabsf(v1), fabsf(v2)));
    sm[t]=am; __syncthreads();
    for (int s=128; s; s>>=1){ if (t<s) sm[t]=fmaxf(sm[t],sm[t+s]); __syncthreads(); }
    float scale = fmaxf(sm[0]/127.0f, 1e-8f);
    float q0 = fminf(fmaxf(rintf(v0/scale), -128.0f), 127.0f);
    float q1 = fminf(fmaxf(rintf(v1/scale), -128.0f), 127.0f);
    float q2 = fminf(fmaxf(rintf(v2/scale), -128.0f), 127.0f);
    qw1[(size_t)h*Cdim + t      ] = (int8_t)q0;
    qw1[(size_t)h*Cdim + t + 256] = (int8_t)q1;
    qw1[(size_t)h*Cdim + t + 512] = (int8_t)q2;
    si[t] = (int)q0 + (int)q1 + (int)q2; __syncthreads();
    for (int s=128; s; s>>=1){ if (t<s) si[t]+=si[t+s]; __syncthreads(); }
    if (t == 0){
        const float* fs = (const float*)scal;
        sa1[h]    = fs[8]*scale;
        icorr1[h] = (128 - (int)fs[9]) * si[0];
    }
}

// ---------------- quantize w2 (per-row symmetric) ----------------
__global__ void k_quant_w2(const float* __restrict__ w2, int8_t* __restrict__ qw2, float* sa2){
    __shared__ float sm[256];
    int c = blockIdx.x, t = threadIdx.x;
    const float* wr = w2 + (size_t)c*Hdim;
    float v[12]; float am = 0.f;
    #pragma unroll
    for (int j=0;j<12;++j){ v[j]=wr[t + j*256]; am=fmaxf(am,fabsf(v[j])); }
    sm[t]=am; __syncthreads();
    for (int s=128; s; s>>=1){ if (t<s) sm[t]=fmaxf(sm[t],sm[t+s]); __syncthreads(); }
    float scale = fmaxf(sm[0]/127.0f, 1e-8f);
    #pragma unroll
    for (int j=0;j<12;++j){
        float q = fminf(fmaxf(rintf(v[j]/scale), -128.0f), 127.0f);
        qw2[(size_t)c*Hdim + t + j*256] = (int8_t)q;
    }
    if (t == 0) sa2[c] = scale;
}

// ---------------- quantize x (asym, recentered by -128) ----------------
__global__ void k_quant_x(const float* __restrict__ x, const float* __restrict__ cs,
                          const unsigned* scal, int8_t* __restrict__ qxs){
    int idx = blockIdx.x*256 + threadIdx.x;
    const int total = Mtok*(Cdim/4);
    if (idx >= total) return;
    const float* fs = (const float*)scal;
    float sc = fs[8], zp = fs[9];
    float4 v = ((const float4*)x)[idx];
    int cb = (idx % (Cdim/4))*4;
    float q0 = fminf(fmaxf(rintf((v.x/cs[cb+0])/sc)+zp, 0.f), 255.f);
    float q1 = fminf(fmaxf(rintf((v.y/cs[cb+1])/sc)+zp, 0.f), 255.f);
    float q2 = fminf(fmaxf(rintf((v.z/cs[cb+2])/sc)+zp, 0.f), 255.f);
    float q3 = fminf(fmaxf(rintf((v.w/cs[cb+3])/sc)+zp, 0.f), 255.f);
    uint32_t pack =  (uint32_t)(uint8_t)((int)q0-128)
                  | ((uint32_t)(uint8_t)((int)q1-128) << 8)
                  | ((uint32_t)(uint8_t)((int)q2-128) << 16)
                  | ((uint32_t)(uint8_t)((int)q3-128) << 24);
    ((uint32_t*)qxs)[idx] = pack;
}

// ---------------- int8 GEMM, 128x128 tile, double-buffered, XCD-swizzled ----------------
#define GLL(src,dst) __builtin_amdgcn_global_load_lds( \
    (const __attribute__((address_space(1))) unsigned*)(src), \
    (__attribute__((address_space(3))) unsigned*)(dst), 16, 0, 0)

// MODE 0: fc1 epilogue, absmax(gelu(h)) only
// MODE 1: fc1 epilogue, quantize gelu(h) -> int8 qout
// MODE 2: fc2 epilogue, out_pre fp32 + global min/max
// MODE 3: fc1 epilogue, gelu(h) -> fp16 hout + absmax
template<int KSTEPS, int MODE, int NY>
__global__ __launch_bounds__(256)
void k_gemm(const int8_t* __restrict__ A, const int8_t* __restrict__ Bw, int N,
            const float* __restrict__ sa, const int* __restrict__ icorr,
            const float* __restrict__ bias, const unsigned* __restrict__ scal,
            int8_t* __restrict__ qout, float* __restrict__ fout, _Float16* __restrict__ hout,
            unsigned* __restrict__ r0, unsigned* __restrict__ r1)
{
    constexpr int K = KSTEPS*64;
    __shared__ __align__(16) int8_t As0[8192];
    __shared__ __align__(16) int8_t Bs0[8192];
    __shared__ __align__(16) int8_t As1[8192];
    __shared__ __align__(16) int8_t Bs1[8192];
    __shared__ float sred[8];
    int t = threadIdx.x, lane = t & 63, wid = t >> 6;
    int wr = wid >> 1, wc = wid & 1;

    // bijective XCD swizzle (m204), by-fast decomposition: consecutive
    // same-XCD blocks share the A row-panel; full B cycles in that XCD's L2.
    int nwg = gridDim.x;
    int q8 = nwg >> 3, r8 = nwg & 7;
    int xcd = blockIdx.x & 7, li = blockIdx.x >> 3;
    int swz = (xcd < r8 ? xcd*(q8+1) : r8*(q8+1) + (xcd - r8)*q8) + li;
    int bx = swz / NY, by = swz % NY;
    size_t brow = (size_t)bx * 128;
    int bcol = by * 128;

    int srow = t >> 2;
    int schunk = (t & 3) ^ ((srow >> 1) & 3);
    const int8_t* ga0 = A  + (brow + srow)*(size_t)K + schunk*16;
    const int8_t* gb0 = Bw + (size_t)(bcol + srow)*K + schunk*16;

    int rsw  = ((lane >> 4) ^ ((lane >> 1) & 3)) << 4;
    int aoff = ((wr*64 + (lane & 15)) << 6) + rsw;
    int boff = ((wc*64 + (lane & 15)) << 6) + rsw;

    v4i acc[4][4] = {};

#define STAGE(AS,BS,ks) do{ \
    const int8_t* pa_ = ga0 + (ks)*64; \
    const int8_t* pb_ = gb0 + (ks)*64; \
    GLL(pa_,                   AS + t*16); \
    GLL(pa_ + (size_t)64*K,    AS + 4096 + t*16); \
    GLL(pb_,                   BS + t*16); \
    GLL(pb_ + (size_t)64*K,    BS + 4096 + t*16); \
}while(0)

#define COMPUTE(AS,BS) do{ \
    v4i a_[4], b_[4]; \
    _Pragma("unroll") \
    for (int m=0;m<4;++m) a_[m] = *(const v4i*)(AS + aoff + (m<<10)); \
    _Pragma("unroll") \
    for (int n=0;n<4;++n) b_[n] = *(const v4i*)(BS + boff + (n<<10)); \
    _Pragma("unroll") \
    for (int m=0;m<4;++m) \
        _Pragma("unroll") \
        for (int n=0;n<4;++n) \
            acc[m][n] = __builtin_amdgcn_mfma_i32_16x16x64_i8(a_[m], b_[n], acc[m][n], 0, 0, 0); \
}while(0)

    // KSTEPS is even for both instantiations (12, 48)
    STAGE(As0,Bs0,0);
    __syncthreads();
    for (int ks = 0; ks < KSTEPS; ks += 2){
        STAGE(As1,Bs1,ks+1);          // prefetch while computing buf0
        COMPUTE(As0,Bs0);
        __syncthreads();              // drains vmcnt for buf1 loads + barrier
        if (ks + 2 < KSTEPS) STAGE(As0,Bs0,ks+2);
        COMPUTE(As1,Bs1);
        __syncthreads();
    }

    int rl = (lane >> 4) * 4;
    if (MODE == 0){
        float amax = 0.f;
        #pragma unroll
        for (int n=0;n<4;++n){
            int col = bcol + wc*64 + n*16 + (lane & 15);
            float s = sa[col]; int ic = icorr[col]; float bb = bias[col];
            #pragma unroll
            for (int m=0;m<4;++m){
                size_t row = brow + wr*64 + m*16 + rl;
                #pragma unroll
                for (int r=0;r<4;++r){
                    if (row + r < (size_t)Mtok){
                        float g = gelu_f(s*(float)(acc[m][n][r] + ic) + bb);
                        amax = fmaxf(amax, fabsf(g));
                    }
                }
            }
        }
        #pragma unroll
        for (int off=32; off; off>>=1) amax = fmaxf(amax, __shfl_down(amax, off));
        if (lane == 0) sred[wid] = amax;
        __syncthreads();
        if (t == 0) atomicMax(r0, fmap(fmaxf(fmaxf(sred[0],sred[1]), fmaxf(sred[2],sred[3]))));
    } else if (MODE == 1){
        float sh = fmaxf(funmap(*scal)/127.0f, 1e-8f);
        #pragma unroll
        for (int n=0;n<4;++n){
            int col = bcol + wc*64 + n*16 + (lane & 15);
            float s = sa[col]; int ic = icorr[col]; float bb = bias[col];
            #pragma unroll
            for (int m=0;m<4;++m){
                size_t row = brow + wr*64 + m*16 + rl;
                #pragma unroll
                for (int r=0;r<4;++r){
                    if (row + r < (size_t)Mtok){
                        float g = gelu_f(s*(float)(acc[m][n][r] + ic) + bb);
                        float qv = fminf(fmaxf(rintf(g/sh), -128.0f), 127.0f);
                        qout[(row + r)*(size_t)N + col] = (int8_t)qv;
                    }
                }
            }
        }
    } else if (MODE == 3){
        float amax = 0.f;
        #pragma unroll
        for (int n=0;n<4;++n){
            int col = bcol + wc*64 + n*16 + (lane & 15);
            float s = sa[col]; int ic = icorr[col]; float bb = bias[col];
            #pragma unroll
            for (int m=0;m<4;++m){
                size_t row = brow + wr*64 + m*16 + rl;
                #pragma unroll
                for (int r=0;r<4;++r){
                    if (row + r < (size_t)Mtok){
                        float g = gelu_f(s*(float)(acc[m][n][r] + ic) + bb);
                        amax = fmaxf(amax, fabsf(g));
                        hout[(row + r)*(size_t)N + col] = (_Float16)g;
                    }
                }
            }
        }
        #pragma unroll
        for (int off=32; off; off>>=1) amax = fmaxf(amax, __shfl_down(amax, off));
        if (lane == 0) sred[wid] = amax;
        __syncthreads();
        if (t == 0) atomicMax(r0, fmap(fmaxf(fmaxf(sred[0],sred[1]), fmaxf(sred[2],sred[3]))));
    } else {
        float sh = fmaxf(funmap(*scal)/127.0f, 1e-8f);
        float lmin =  __builtin_inff(), lmax = -__builtin_inff();
        #pragma unroll
        for (int n=0;n<4;++n){
            int col = bcol + wc*64 + n*16 + (lane & 15);
            float s = sh * sa[col]; float bb = bias[col];
            #pragma unroll
            for (int m=0;m<4;++m){
                size_t row = brow + wr*64 + m*16 + rl;
                #pragma unroll
                for (int r=0;r<4;++r){
                    if (row + r < (size_t)Mtok){
                        float o = s*(float)acc[m][n][r] + bb;
                        fout[(row + r)*(size_t)N + col] = o;
                        lmin = fminf(lmin, o); lmax = fmaxf(lmax, o);
                    }
                }
            }
        }
        #pragma unroll
        for (int off=32; off; off>>=1){
            lmin = fminf(lmin, __shfl_down(lmin, off));
            lmax = fmaxf(lmax, __shfl_down(lmax, off));
        }
        if (lane == 0){ sred[wid] = lmin; sred[4+wid] = lmax; }
        __syncthreads();
        if (t == 0){
            atomicMin(r0, fmap(fminf(fminf(sred[0],sred[1]), fminf(sred[2],sred[3]))));
            atomicMax(r1, fmap(fmaxf(fmaxf(sred[4],sred[5]), fmaxf(sred[6],sred[7]))));
        }
    }
#undef STAGE
#undef COMPUTE
}

// ---------------- fp16 h -> int8 requant ----------------
struct alignas(16) H8 { _Float16 v[8]; };
__global__ void k_requant(const _Float16* __restrict__ h, const unsigned* __restrict__ scal,
                          int8_t* __restrict__ qh){
    int idx = blockIdx.x*256 + threadIdx.x;
    const int total = Mtok*(Hdim/8);
    if (idx >= total) return;
    float sh = fmaxf(funmap(scal[0])/127.0f, 1e-8f);
    H8 h8 = ((const H8*)h)[idx];
    uint32_t lo = 0, hi = 0;
    #pragma unroll
    for (int j=0;j<4;++j){
        float qv = fminf(fmaxf(rintf((float)h8.v[j]/sh), -128.0f), 127.0f);
        lo |= ((uint32_t)(uint8_t)(int)qv) << (8*j);
    }
    #pragma unroll
    for (int j=0;j<4;++j){
        float qv = fminf(fmaxf(rintf((float)h8.v[4+j]/sh), -128.0f), 127.0f);
        hi |= ((uint32_t)(uint8_t)(int)qv) << (8*j);
    }
    uint2 pk; pk.x = lo; pk.y = hi;
    ((uint2*)qh)[idx] = pk;
}

// ---------------- final asym requant of out ----------------
__global__ void k_final(const float* __restrict__ outpre, const unsigned* __restrict__ scal,
                        float* __restrict__ out){
    int idx = blockIdx.x*256 + threadIdx.x;
    const int total = Mtok*(Cdim/4);
    if (idx >= total) return;
    float omin = fminf(funmap(scal[1]), 0.0f);
    float omax = fmaxf(funmap(scal[2]), 0.0f);
    float sc = fmaxf((omax - omin)/255.0f, 1e-8f);
    float zp = rintf(-omin/sc);
    float4 v = ((const float4*)outpre)[idx];
    v.x = (fminf(fmaxf(rintf(v.x/sc)+zp, 0.f), 255.f) - zp)*sc;
    v.y = (fminf(fmaxf(rintf(v.y/sc)+zp, 0.f), 255.f) - zp)*sc;
    v.z = (fminf(fmaxf(rintf(v.z/sc)+zp, 0.f), 255.f) - zp)*sc;
    v.w = (fminf(fmaxf(rintf(v.w/sc)+zp, 0.f), 255.f) - zp)*sc;
    ((float4*)out)[idx] = v;
}

extern "C" void kernel_launch(void* const* d_in, const int* in_sizes, int n_in,
                              void* d_out, int out_size, void* d_ws, size_t ws_size,
                              hipStream_t stream)
{
    if (n_in < 5) return;
    const float* x  = (const float*)d_in[0];
    const float* w1 = (const float*)d_in[1];
    const float* b1 = (const float*)d_in[2];
    const float* w2 = (const float*)d_in[3];
    const float* b2 = (const float*)d_in[4];
    float* out = (float*)d_out;

    uint8_t* w = (uint8_t*)d_ws;
    size_t off = 0;
    unsigned* scal  = (unsigned*)(w + off); off += 256;
    unsigned* xminU = (unsigned*)(w + off); off += 3072;
    unsigned* xmaxU = (unsigned*)(w + off); off += 3072;
    unsigned* wmaxU = (unsigned*)(w + off); off += 3072;
    float*    cs    = (float*)   (w + off); off += 3072;
    float*    sa1   = (float*)   (w + off); off += 12288;
    int*      icorr1= (int*)     (w + off); off += 12288;
    float*    sa2   = (float*)   (w + off); off += 3072;
    off = (off + 255) & ~(size_t)255;
    int8_t*   qw1   = (int8_t*)  (w + off); off += (size_t)Hdim*Cdim;
    int8_t*   qw2   = (int8_t*)  (w + off); off += (size_t)Cdim*Hdim;
    int8_t*   qxs   = (int8_t*)  (w + off); off += (size_t)MP*Cdim;
    int8_t*   qh    = (int8_t*)  (w + off); off += (size_t)MP*Hdim;
    size_t off_big = off;
    // 3-GEMM path: outpre fp32 only.  fp16 path: hbuf fp16 (outpre overlaid in it).
    float*    outpre= (float*)   (w + off_big);
    _Float16* hbuf  = (_Float16*)(w + off_big);
    size_t need_3g  = off_big + (size_t)Mtok*Cdim*4;
    size_t need_h16 = off_big + (size_t)Mtok*Hdim*2;
    if (ws_size < need_3g) return;
    bool use_h16 = (ws_size >= need_h16);   // constant across calls -> graph-safe

    k_init<<<3, 256, 0, stream>>>(scal, xminU, xmaxU, wmaxU);
    k_colstats_x<<<512, 256, 0, stream>>>(x, xminU, xmaxU);
    k_colmax_w1<<<512, 256, 0, stream>>>(w1, wmaxU);
    k_scale0<<<1, 256, 0, stream>>>(xminU, xmaxU, wmaxU, cs, scal);
    k_quant_w1<<<Hdim, 256, 0, stream>>>(w1, cs, scal, qw1, sa1, icorr1);
    k_quant_w2<<<Cdim, 256, 0, stream>>>(w2, qw2, sa2);
    k_quant_x<<<(Mtok*(Cdim/4) + 255)/256, 256, 0, stream>>>(x, cs, scal, qxs);

    if (use_h16){
        k_gemm<12,3,24><<<2376, 256, 0, stream>>>(qxs, qw1, Hdim, sa1, icorr1, b1, scal,
                                                  nullptr, nullptr, hbuf, &scal[0], nullptr);
        k_requant<<<(Mtok*(Hdim/8) + 255)/256, 256, 0, stream>>>(hbuf, scal, qh);
    } else {
        k_gemm<12,0,24><<<2376, 256, 0, stream>>>(qxs, qw1, Hdim, sa1, icorr1, b1, scal,
                                                  nullptr, nullptr, nullptr, &scal[0], nullptr);
        k_gemm<12,1,24><<<2376, 256, 0, stream>>>(qxs, qw1, Hdim, sa1, icorr1, b1, scal,
                                                  qh, nullptr, nullptr, nullptr, nullptr);
    }
    k_gemm<48,2,6><<<594, 256, 0, stream>>>(qh, qw2, Cdim, sa2, nullptr, b2, scal,
                                            nullptr, outpre, nullptr, &scal[1], &scal[2]);

    k_final<<<(Mtok*(Cdim/4) + 255)/256, 256, 0, stream>>>(outpre, scal, out);
}